// Round 2
// baseline (3153.135 us; speedup 1.0000x reference)
//
#include <hip/hip_runtime.h>
#include <stdint.h>

#define H   300
#define HP  320
#define CAP 32     // max incoming bonds per atom (Binomial(400k,1/200k) max ~13)

using bf8 = __attribute__((ext_vector_type(8))) short;   // 8 x bf16
using f4  = __attribute__((ext_vector_type(4))) float;   // MFMA acc

__device__ __forceinline__ float bf2f(unsigned short u){
    union { unsigned int i; float f; } v; v.i = ((unsigned int)u) << 16; return v.f;
}
__device__ __forceinline__ unsigned short f2bf(float x){
    unsigned int u = __builtin_bit_cast(unsigned int, x);
    u = (u + 0x7FFFu + ((u >> 16) & 1u)) >> 16;   // RNE
    return (unsigned short)u;
}

// ---------------------------------------------------------------------------
// Incoming-bond bucket list: bucket[a][0..cnt[a]) = bond indices with dst==a
// ---------------------------------------------------------------------------
__global__ void fill_k(const int* __restrict__ b_dst, int* __restrict__ cnt,
                       int* __restrict__ bucket, int nB){
    int e = blockIdx.x * 256 + threadIdx.x;
    if (e >= nB) return;
    int d = b_dst[e];
    int slot = atomicAdd(&cnt[d], 1);
    if (slot < CAP) bucket[(long)d * CAP + slot] = e;
}

// ---------------------------------------------------------------------------
// Weight prep: W [Kact][H] fp32 -> Wt [320][Kp] bf16, transposed + zero-padded
// ---------------------------------------------------------------------------
__global__ void prep_wt(const float* __restrict__ W, unsigned short* __restrict__ Wt,
                        int Kact, int Kp){
    int idx = blockIdx.x * 256 + threadIdx.x;
    if (idx >= 320 * Kp) return;
    int n = idx / Kp, k = idx % Kp;
    float v = (n < H && k < Kact) ? W[(long)k * H + n] : 0.f;
    Wt[idx] = f2bf(v);
}

// W_o [900][300] -> Wt_o [320][960]: k = blk*320+kk maps to W row blk*300+kk
__global__ void prep_wto(const float* __restrict__ W, unsigned short* __restrict__ Wt){
    int idx = blockIdx.x * 256 + threadIdx.x;
    if (idx >= 320 * 960) return;
    int n = idx / 960, k = idx % 960;
    int blk = k / HP, kk = k % HP;
    float v = (n < H && kk < H) ? W[((long)blk * H + kk) * H + n] : 0.f;
    Wt[idx] = f2bf(v);
}

// ---------------------------------------------------------------------------
// Unified GEMM: out[rows][320] = epilogue( A[rows][K] @ Wt^T )
// MODE 0: A = Afp fp32 [rows][Kact], out = relu(acc)               (inputs)
// MODE 2: A row e = sum_{incoming(b_src[e])} msg[j] - msg[b2revb[e]],
//         out = relu(bond_in + acc)                                (msg step)
// MODE 3: A = [bfA | bfB | bfA*bfB] (K=960), out = relu(acc + b_o) (atom_h)
// BM=64, BN=320(all), 256 threads = 4 waves (1M x 4N), 16x16x32 bf16 MFMA
// ---------------------------------------------------------------------------
template<int MODE>
__global__ __launch_bounds__(256, 2)
void gemm_k(const float* __restrict__ Afp, int Kact,
            const unsigned short* __restrict__ Wt, int Kp,
            const unsigned short* __restrict__ bfA,   // M2: msg_in; M3: input_atom
            const unsigned short* __restrict__ bfB,   // M3: a_msg (bf16)
            const unsigned short* __restrict__ bond_in, // M2: input_bond
            const float* __restrict__ b_o,            // M3
            const int* __restrict__ b_src,
            const int* __restrict__ b2revb,
            const int* __restrict__ cnt,
            const int* __restrict__ bucket,
            unsigned short* __restrict__ outb)        // bf16 [rows][320]
{
    __shared__ unsigned short lds[2][(64 + 320) * 40];   // 80B row stride, 61440 B
    const int tid = threadIdx.x;
    const int rowBase = blockIdx.x * 64;
    const int KS = Kp / 32;

    const int r = tid >> 2;          // staged row 0..63
    const int c = tid & 3;           // k-chunk 0..3 (8 elems each)
    const int e = rowBase + r;

    int grev = 0, gbase = 0, gdeg = 0;
    if constexpr (MODE == 2){
        int s = b_src[e];
        grev  = b2revb[e];
        gbase = s * CAP;
        gdeg  = cnt[s]; if (gdeg > CAP) gdeg = CAP;
    }

    bf8 sa;        // staged A chunk (8 bf16)
    bf8 sb[5];     // staged B chunks

    auto load_stage = [&](int ks){
        const int k0 = ks * 32 + c * 8;
        if constexpr (MODE == 0) {
            #pragma unroll
            for (int j = 0; j < 8; j++){
                int k = k0 + j;
                float v = (k < Kact) ? Afp[(long)e * Kact + k] : 0.f;
                sa[j] = (short)f2bf(v);
            }
        } else if constexpr (MODE == 2) {
            float accf[8];
            #pragma unroll
            for (int j = 0; j < 8; j++) accf[j] = 0.f;
            for (int j = 0; j < gdeg; ++j){
                int be = bucket[gbase + j];
                bf8 mm = *(const bf8*)(bfA + (long)be * HP + k0);
                #pragma unroll
                for (int t2 = 0; t2 < 8; t2++) accf[t2] += bf2f((unsigned short)mm[t2]);
            }
            bf8 rv = *(const bf8*)(bfA + (long)grev * HP + k0);
            #pragma unroll
            for (int t2 = 0; t2 < 8; t2++)
                sa[t2] = (short)f2bf(accf[t2] - bf2f((unsigned short)rv[t2]));
        } else { // MODE 3: K blocks of 320
            int blk = ks / 10;
            int kk0 = (ks % 10) * 32 + c * 8;
            if (blk == 0) {
                sa = *(const bf8*)(bfA + (long)e * HP + kk0);
            } else if (blk == 1) {
                sa = *(const bf8*)(bfB + (long)e * HP + kk0);
            } else {
                bf8 a = *(const bf8*)(bfA + (long)e * HP + kk0);
                bf8 b = *(const bf8*)(bfB + (long)e * HP + kk0);
                #pragma unroll
                for (int t2 = 0; t2 < 8; t2++)
                    sa[t2] = (short)f2bf(bf2f((unsigned short)a[t2]) * bf2f((unsigned short)b[t2]));
            }
        }
        // B tile: 320 n-rows x 32 k = 1280 chunks of 8 bf16; 5 per thread
        #pragma unroll
        for (int i = 0; i < 5; i++){
            int chunk = tid + i * 256;
            int n = chunk >> 2, kc = chunk & 3;
            sb[i] = *(const bf8*)(Wt + (long)n * Kp + ks * 32 + kc * 8);
        }
    };

    auto write_stage = [&](int buf){
        *(bf8*)&lds[buf][r * 40 + c * 8] = sa;
        #pragma unroll
        for (int i = 0; i < 5; i++){
            int chunk = tid + i * 256;
            int n = chunk >> 2, kc = chunk & 3;
            *(bf8*)&lds[buf][(64 + n) * 40 + kc * 8] = sb[i];
        }
    };

    const int w    = tid >> 6;          // wave 0..3 -> N stripe of 80
    const int lane = tid & 63;
    const int lr   = lane & 15;
    const int lk   = (lane >> 4) * 8;   // k offset (ushorts)

    f4 acc[4][5];
    #pragma unroll
    for (int m = 0; m < 4; m++)
        #pragma unroll
        for (int n = 0; n < 5; n++)
            acc[m][n] = (f4){0.f, 0.f, 0.f, 0.f};

    load_stage(0);
    write_stage(0);
    __syncthreads();
    int cur = 0;
    for (int ks = 0; ks < KS; ++ks){
        if (ks + 1 < KS) load_stage(ks + 1);      // next-tile loads in flight
        bf8 af[4], bfr[5];
        #pragma unroll
        for (int m = 0; m < 4; m++)
            af[m] = *(const bf8*)&lds[cur][(m * 16 + lr) * 40 + lk];
        #pragma unroll
        for (int n = 0; n < 5; n++)
            bfr[n] = *(const bf8*)&lds[cur][(64 + w * 80 + n * 16 + lr) * 40 + lk];
        #pragma unroll
        for (int m = 0; m < 4; m++)
            #pragma unroll
            for (int n = 0; n < 5; n++)
                acc[m][n] = __builtin_amdgcn_mfma_f32_16x16x32_bf16(af[m], bfr[n], acc[m][n], 0, 0, 0);
        if (ks + 1 < KS) write_stage(cur ^ 1);
        __syncthreads();
        cur ^= 1;
    }

    // epilogue: C/D layout col = lane&15, row = (lane>>4)*4 + reg
    const int rgrp = (lane >> 4) * 4;
    #pragma unroll
    for (int m = 0; m < 4; m++){
        #pragma unroll
        for (int n = 0; n < 5; n++){
            int col = w * 80 + n * 16 + lr;
            #pragma unroll
            for (int q = 0; q < 4; q++){
                int row = m * 16 + rgrp + q;
                int gr  = rowBase + row;
                float v = acc[m][n][q];
                if constexpr (MODE == 2) v += bf2f(bond_in[(long)gr * HP + col]);
                if constexpr (MODE == 3) v += (col < H ? b_o[col] : 0.f);
                v = fmaxf(v, 0.f);
                outb[(long)gr * HP + col] = f2bf(v);
            }
        }
    }
}

// ---------------------------------------------------------------------------
// a_msg[a] = sum of final msg rows with dst==a (bf16 out, full 320 cols)
// ---------------------------------------------------------------------------
__global__ __launch_bounds__(320)
void amsg_k(const unsigned short* __restrict__ msg, const int* __restrict__ cnt,
            const int* __restrict__ bucket, unsigned short* __restrict__ amsg){
    int a = blockIdx.x;
    int t = threadIdx.x;
    int dg = cnt[a]; if (dg > CAP) dg = CAP;
    long base = (long)a * CAP;
    float s = 0.f;
    for (int j = 0; j < dg; ++j)
        s += bf2f(msg[(long)bucket[base + j] * HP + t]);
    amsg[(long)a * HP + t] = f2bf(s);
}

// ---------------------------------------------------------------------------
// Readout: per-molecule mean over sorted mol_ids (binary-search range)
// ---------------------------------------------------------------------------
__global__ __launch_bounds__(320)
void readout_k(const unsigned short* __restrict__ atom_h,
               const int* __restrict__ mol_ids, int nAtoms,
               float* __restrict__ out){
    int m = blockIdx.x;
    int t = threadIdx.x;
    int lo = 0, hi = nAtoms;
    while (lo < hi){ int mid = (lo + hi) >> 1; if (mol_ids[mid] < m) lo = mid + 1; else hi = mid; }
    int lo2 = lo, hi2 = nAtoms;
    while (lo2 < hi2){ int mid = (lo2 + hi2) >> 1; if (mol_ids[mid] < m + 1) lo2 = mid + 1; else hi2 = mid; }
    if (t < H){
        float s = 0.f;
        for (int a = lo; a < lo2; ++a) s += bf2f(atom_h[(long)a * HP + t]);
        int c2 = lo2 - lo;
        out[(long)m * H + t] = s / (float)(c2 > 0 ? c2 : 1);
    }
}

// ---------------------------------------------------------------------------
extern "C" void kernel_launch(void* const* d_in, const int* in_sizes, int n_in,
                              void* d_out, int out_size, void* d_ws, size_t ws_size,
                              hipStream_t stream){
    const float* f_atoms  = (const float*)d_in[0];
    const float* f_bonds  = (const float*)d_in[1];
    const float* W_i_atom = (const float*)d_in[2];
    const float* W_i_bond = (const float*)d_in[3];
    const float* W_h      = (const float*)d_in[4];
    const float* W_o      = (const float*)d_in[5];
    const float* b_o      = (const float*)d_in[6];
    const int* b_src   = (const int*)d_in[7];
    const int* b2revb  = (const int*)d_in[9];
    const int* b_dst   = (const int*)d_in[8];
    const int* mol_ids = (const int*)d_in[10];

    const int nA = in_sizes[10];          // 200000 (mol_ids is per-atom)
    const int nB = in_sizes[7];           // 400000
    const int nM = out_size / H;          // 4096

    char* p = (char*)d_ws;
    auto alloc = [&](size_t bytes){ char* q = p; p += (bytes + 255) & ~(size_t)255; return q; };
    unsigned short* Wt_ia = (unsigned short*)alloc((size_t)320 * 160 * 2);
    unsigned short* Wt_ib = (unsigned short*)alloc((size_t)320 * 160 * 2);
    unsigned short* Wt_h  = (unsigned short*)alloc((size_t)3 * 320 * 320 * 2);
    unsigned short* Wt_o  = (unsigned short*)alloc((size_t)320 * 960 * 2);
    int* cnt    = (int*)alloc((size_t)nA * 4);
    int* bucket = (int*)alloc((size_t)nA * CAP * 4);
    unsigned short* input_atom = (unsigned short*)alloc((size_t)nA * HP * 2);
    unsigned short* input_bond = (unsigned short*)alloc((size_t)nB * HP * 2);
    unsigned short* msgA  = (unsigned short*)alloc((size_t)nB * HP * 2);
    unsigned short* msgB  = (unsigned short*)alloc((size_t)nB * HP * 2);
    unsigned short* amsg   = msgB;        // alias: msgB dead after step 3
    unsigned short* atom_h = input_bond;  // alias: input_bond dead after step 3

    if ((size_t)(p - (char*)d_ws) > ws_size) return;  // diagnostic: ws too small

    // adjacency buckets
    hipMemsetAsync(cnt, 0, (size_t)nA * 4, stream);
    fill_k<<<dim3((nB + 255) / 256), dim3(256), 0, stream>>>(b_dst, cnt, bucket, nB);

    // weight prep
    prep_wt<<<dim3((320*160 + 255)/256), dim3(256), 0, stream>>>(W_i_atom, Wt_ia, 133, 160);
    prep_wt<<<dim3((320*160 + 255)/256), dim3(256), 0, stream>>>(W_i_bond, Wt_ib, 147, 160);
    for (int d = 0; d < 3; d++)
        prep_wt<<<dim3((320*320 + 255)/256), dim3(256), 0, stream>>>(
            W_h + (size_t)d * H * H, Wt_h + (size_t)d * 320 * 320, 300, 320);
    prep_wto<<<dim3((320*960 + 255)/256), dim3(256), 0, stream>>>(W_o, Wt_o);

    // input projections
    gemm_k<0><<<dim3(nA/64), dim3(256), 0, stream>>>(
        f_atoms, 133, Wt_ia, 160, nullptr, nullptr, nullptr, nullptr,
        nullptr, nullptr, nullptr, nullptr, input_atom);
    gemm_k<0><<<dim3(nB/64), dim3(256), 0, stream>>>(
        f_bonds, 147, Wt_ib, 160, nullptr, nullptr, nullptr, nullptr,
        nullptr, nullptr, nullptr, nullptr, input_bond);

    // message steps (msg0 = input_bond)
    gemm_k<2><<<dim3(nB/64), dim3(256), 0, stream>>>(
        nullptr, 0, Wt_h + 0 * 320 * 320, 320, input_bond, nullptr, input_bond, nullptr,
        b_src, b2revb, cnt, bucket, msgA);
    gemm_k<2><<<dim3(nB/64), dim3(256), 0, stream>>>(
        nullptr, 0, Wt_h + 1 * 320 * 320, 320, msgA, nullptr, input_bond, nullptr,
        b_src, b2revb, cnt, bucket, msgB);
    gemm_k<2><<<dim3(nB/64), dim3(256), 0, stream>>>(
        nullptr, 0, Wt_h + 2 * 320 * 320, 320, msgB, nullptr, input_bond, nullptr,
        b_src, b2revb, cnt, bucket, msgA);

    // final per-atom aggregation (bf16)
    amsg_k<<<dim3(nA), dim3(320), 0, stream>>>(msgA, cnt, bucket, amsg);

    // atom_h = relu([input_atom | amsg | input_atom*amsg] @ W_o + b_o)
    gemm_k<3><<<dim3(nA/64), dim3(256), 0, stream>>>(
        nullptr, 0, Wt_o, 960, input_atom, amsg, nullptr, b_o,
        nullptr, nullptr, nullptr, nullptr, atom_h);

    // per-molecule mean
    readout_k<<<dim3(nM), dim3(320), 0, stream>>>(atom_h, mol_ids, nA, (float*)d_out);
}

// Round 3
// 2955.508 us; speedup vs baseline: 1.0669x; 1.0669x over previous
//
#include <hip/hip_runtime.h>
#include <stdint.h>

#define H   300
#define HP  320
#define CAP 32     // max incoming bonds per atom (Binomial(400k,1/200k) max ~13)

using bf8 = __attribute__((ext_vector_type(8))) short;   // 8 x bf16
using f4  = __attribute__((ext_vector_type(4))) float;   // MFMA acc

__device__ __forceinline__ float bf2f(unsigned short u){
    union { unsigned int i; float f; } v; v.i = ((unsigned int)u) << 16; return v.f;
}
__device__ __forceinline__ unsigned short f2bf(float x){
    unsigned int u = __builtin_bit_cast(unsigned int, x);
    u = (u + 0x7FFFu + ((u >> 16) & 1u)) >> 16;   // RNE
    return (unsigned short)u;
}

// ---------------------------------------------------------------------------
// Incoming-bond bucket list: bucket[a][0..cnt[a]) = bond indices with dst==a
// ---------------------------------------------------------------------------
__global__ void fill_k(const int* __restrict__ b_dst, int* __restrict__ cnt,
                       int* __restrict__ bucket, int nB){
    int e = blockIdx.x * 256 + threadIdx.x;
    if (e >= nB) return;
    int d = b_dst[e];
    int slot = atomicAdd(&cnt[d], 1);
    if (slot < CAP) bucket[(long)d * CAP + slot] = e;
}

// ---------------------------------------------------------------------------
// Weight prep: W [Kact][H] fp32 -> Wt [320][Kp] bf16, transposed + zero-padded
// ---------------------------------------------------------------------------
__global__ void prep_wt(const float* __restrict__ W, unsigned short* __restrict__ Wt,
                        int Kact, int Kp){
    int idx = blockIdx.x * 256 + threadIdx.x;
    if (idx >= 320 * Kp) return;
    int n = idx / Kp, k = idx % Kp;
    float v = (n < H && k < Kact) ? W[(long)k * H + n] : 0.f;
    Wt[idx] = f2bf(v);
}

// W_o [900][300] -> Wt_o [320][960]: k = blk*320+kk maps to W row blk*300+kk
__global__ void prep_wto(const float* __restrict__ W, unsigned short* __restrict__ Wt){
    int idx = blockIdx.x * 256 + threadIdx.x;
    if (idx >= 320 * 960) return;
    int n = idx / 960, k = idx % 960;
    int blk = k / HP, kk = k % HP;
    float v = (n < H && kk < H) ? W[((long)blk * H + kk) * H + n] : 0.f;
    Wt[idx] = f2bf(v);
}

// ---------------------------------------------------------------------------
// Unified GEMM: out[rows][320] = epilogue( A[rows][K] @ Wt^T )
// A tile (64 x 320) staged into LDS ONCE per section; B (weights, L2-resident)
// register-prefetched one K-step ahead into a single LDS buffer.
// MODE 0: A = Afp fp32, out = relu(acc)                            (inputs)
// MODE 2: A row e = sum_{incoming(b_src[e])} msg[j] - msg[b2revb[e]],
//         out = relu(bond_in + acc)                                (msg step)
// MODE 3: A = [bfA | bfB | bfA*bfB] (3 sections), out = relu(acc+b_o)
// BM=64, BN=320(all), 256 threads = 4 waves (1M x 4N), 16x16x32 bf16 MFMA
// ---------------------------------------------------------------------------
template<int MODE>
__global__ __launch_bounds__(256, 2)
void gemm_k(const float* __restrict__ Afp, int Kact,
            const unsigned short* __restrict__ Wt,
            const unsigned short* __restrict__ bfA,   // M2: msg_in; M3: input_atom
            const unsigned short* __restrict__ bfB,   // M3: a_msg (bf16)
            const unsigned short* __restrict__ bond_in, // M2: input_bond
            const float* __restrict__ b_o,            // M3
            const int* __restrict__ b_src,
            const int* __restrict__ b2revb,
            const int* __restrict__ cnt,
            const int* __restrict__ bucket,
            unsigned short* __restrict__ outb)        // bf16 [rows][320]
{
    constexpr int KS   = (MODE == 0) ? 5 : 10;        // K-steps per section
    constexpr int SEC  = (MODE == 3) ? 3 : 1;
    constexpr int Ktot = (MODE == 0) ? 160 : (MODE == 3 ? 960 : 320);
    constexpr int TS   = SEC * KS;

    __shared__ unsigned short ldsA[64 * 328];         // 41984 B, stride 328 ush
    __shared__ unsigned short ldsB[4 * 320 * 8];      // 20480 B, [kc][n][8]

    const int tid = threadIdx.x;
    const int rowBase = blockIdx.x * 64;
    const int r = tid >> 2, c = tid & 3;              // staged row / k-chunk
    const int e = rowBase + r;

    int grev = 0, gbase = 0, gdeg = 0;
    int be0 = 0, be1 = 0, be2 = 0, be3 = 0;
    if constexpr (MODE == 2){
        int s = b_src[e];
        grev  = b2revb[e];
        gbase = s * CAP;
        gdeg  = cnt[s]; if (gdeg > CAP) gdeg = CAP;
        if (gdeg > 0) be0 = bucket[gbase + 0];
        if (gdeg > 1) be1 = bucket[gbase + 1];
        if (gdeg > 2) be2 = bucket[gbase + 2];
        if (gdeg > 3) be3 = bucket[gbase + 3];
    }

    bf8 sbreg[5];                                     // B prefetch registers
    auto loadB = [&](int t){
        #pragma unroll
        for (int i = 0; i < 5; i++){
            int chunk = tid + i * 256;
            int n = chunk >> 2, kc = chunk & 3;
            sbreg[i] = *(const bf8*)(Wt + (long)n * Ktot + t * 32 + kc * 8);
        }
    };
    auto writeB = [&](){
        #pragma unroll
        for (int i = 0; i < 5; i++){
            int chunk = tid + i * 256;
            int n = chunk >> 2, kc = chunk & 3;
            *(bf8*)&ldsB[kc * 2560 + n * 8] = sbreg[i];
        }
    };

    auto stageA = [&](int sec){
        #pragma unroll
        for (int i = 0; i < KS; i++){
            const int kk0 = i * 32 + c * 8;
            bf8 v;
            if constexpr (MODE == 0){
                #pragma unroll
                for (int j = 0; j < 8; j++){
                    int k = kk0 + j;
                    float f = (k < Kact) ? Afp[(long)e * Kact + k] : 0.f;
                    v[j] = (short)f2bf(f);
                }
            } else if constexpr (MODE == 2){
                float accf[8];
                #pragma unroll
                for (int q = 0; q < 8; q++) accf[q] = 0.f;
                auto addrow = [&](int be){
                    bf8 mm = *(const bf8*)(bfA + (long)be * HP + kk0);
                    #pragma unroll
                    for (int q = 0; q < 8; q++) accf[q] += bf2f((unsigned short)mm[q]);
                };
                if (gdeg > 0) addrow(be0);
                if (gdeg > 1) addrow(be1);
                if (gdeg > 2) addrow(be2);
                if (gdeg > 3) addrow(be3);
                for (int j = 4; j < gdeg; ++j) addrow(bucket[gbase + j]);
                bf8 rv = *(const bf8*)(bfA + (long)grev * HP + kk0);
                #pragma unroll
                for (int q = 0; q < 8; q++)
                    v[q] = (short)f2bf(accf[q] - bf2f((unsigned short)rv[q]));
            } else { // MODE 3
                if (sec == 0){
                    v = *(const bf8*)(bfA + (long)e * HP + kk0);
                } else if (sec == 1){
                    v = *(const bf8*)(bfB + (long)e * HP + kk0);
                } else {
                    bf8 a = *(const bf8*)(bfA + (long)e * HP + kk0);
                    bf8 b = *(const bf8*)(bfB + (long)e * HP + kk0);
                    #pragma unroll
                    for (int q = 0; q < 8; q++)
                        v[q] = (short)f2bf(bf2f((unsigned short)a[q]) * bf2f((unsigned short)b[q]));
                }
            }
            *(bf8*)&ldsA[r * 328 + kk0] = v;
        }
    };

    const int w    = tid >> 6;          // wave -> N stripe of 80
    const int lane = tid & 63;
    const int lr   = lane & 15;
    const int g    = lane >> 4;         // k-subchunk 0..3

    f4 acc[4][5];
    #pragma unroll
    for (int m = 0; m < 4; m++)
        #pragma unroll
        for (int n = 0; n < 5; n++)
            acc[m][n] = (f4){0.f, 0.f, 0.f, 0.f};

    loadB(0);
    for (int t = 0; t < TS; ++t){
        const int ks = t % KS;
        if (ks == 0) stageA(t / KS);     // once per section (prev sync guards LDS)
        writeB();                        // B(t): regs -> LDS
        if (t + 1 < TS) loadB(t + 1);    // prefetch B(t+1), in flight across MFMAs
        __syncthreads();                 // A + B visible
        bf8 af[4], bfr[5];
        #pragma unroll
        for (int m = 0; m < 4; m++)
            af[m] = *(const bf8*)&ldsA[(m * 16 + lr) * 328 + ks * 32 + g * 8];
        #pragma unroll
        for (int n = 0; n < 5; n++)
            bfr[n] = *(const bf8*)&ldsB[g * 2560 + (w * 80 + n * 16 + lr) * 8];
        #pragma unroll
        for (int m = 0; m < 4; m++)
            #pragma unroll
            for (int n = 0; n < 5; n++)
                acc[m][n] = __builtin_amdgcn_mfma_f32_16x16x32_bf16(af[m], bfr[n], acc[m][n], 0, 0, 0);
        __syncthreads();                 // readers done before next writeB/stageA
    }

    // epilogue: C/D layout col = lane&15 (+16*n+80*w), row = (lane>>4)*4 + q
    const int rgrp = g * 4;
    #pragma unroll
    for (int m = 0; m < 4; m++){
        #pragma unroll
        for (int n = 0; n < 5; n++){
            int col = w * 80 + n * 16 + lr;
            #pragma unroll
            for (int q = 0; q < 4; q++){
                int row = m * 16 + rgrp + q;
                int gr  = rowBase + row;
                float v = acc[m][n][q];
                if constexpr (MODE == 2) v += bf2f(bond_in[(long)gr * HP + col]);
                if constexpr (MODE == 3) v += (col < H ? b_o[col] : 0.f);
                v = fmaxf(v, 0.f);
                outb[(long)gr * HP + col] = f2bf(v);
            }
        }
    }
}

// ---------------------------------------------------------------------------
// a_msg[a] = sum of final msg rows with dst==a (bf16 out, full 320 cols)
// ---------------------------------------------------------------------------
__global__ __launch_bounds__(320)
void amsg_k(const unsigned short* __restrict__ msg, const int* __restrict__ cnt,
            const int* __restrict__ bucket, unsigned short* __restrict__ amsg){
    int a = blockIdx.x;
    int t = threadIdx.x;
    int dg = cnt[a]; if (dg > CAP) dg = CAP;
    long base = (long)a * CAP;
    float s = 0.f;
    for (int j = 0; j < dg; ++j)
        s += bf2f(msg[(long)bucket[base + j] * HP + t]);
    amsg[(long)a * HP + t] = f2bf(s);
}

// ---------------------------------------------------------------------------
// Readout: per-molecule mean over sorted mol_ids (binary-search range)
// ---------------------------------------------------------------------------
__global__ __launch_bounds__(320)
void readout_k(const unsigned short* __restrict__ atom_h,
               const int* __restrict__ mol_ids, int nAtoms,
               float* __restrict__ out){
    int m = blockIdx.x;
    int t = threadIdx.x;
    int lo = 0, hi = nAtoms;
    while (lo < hi){ int mid = (lo + hi) >> 1; if (mol_ids[mid] < m) lo = mid + 1; else hi = mid; }
    int lo2 = lo, hi2 = nAtoms;
    while (lo2 < hi2){ int mid = (lo2 + hi2) >> 1; if (mol_ids[mid] < m + 1) lo2 = mid + 1; else hi2 = mid; }
    if (t < H){
        float s = 0.f;
        for (int a = lo; a < lo2; ++a) s += bf2f(atom_h[(long)a * HP + t]);
        int c2 = lo2 - lo;
        out[(long)m * H + t] = s / (float)(c2 > 0 ? c2 : 1);
    }
}

// ---------------------------------------------------------------------------
extern "C" void kernel_launch(void* const* d_in, const int* in_sizes, int n_in,
                              void* d_out, int out_size, void* d_ws, size_t ws_size,
                              hipStream_t stream){
    const float* f_atoms  = (const float*)d_in[0];
    const float* f_bonds  = (const float*)d_in[1];
    const float* W_i_atom = (const float*)d_in[2];
    const float* W_i_bond = (const float*)d_in[3];
    const float* W_h      = (const float*)d_in[4];
    const float* W_o      = (const float*)d_in[5];
    const float* b_o      = (const float*)d_in[6];
    const int* b_src   = (const int*)d_in[7];
    const int* b_dst   = (const int*)d_in[8];
    const int* b2revb  = (const int*)d_in[9];
    const int* mol_ids = (const int*)d_in[10];

    const int nA = in_sizes[10];          // 200000 (mol_ids is per-atom)
    const int nB = in_sizes[7];           // 400000
    const int nM = out_size / H;          // 4096

    char* p = (char*)d_ws;
    auto alloc = [&](size_t bytes){ char* q = p; p += (bytes + 255) & ~(size_t)255; return q; };
    unsigned short* Wt_ia = (unsigned short*)alloc((size_t)320 * 160 * 2);
    unsigned short* Wt_ib = (unsigned short*)alloc((size_t)320 * 160 * 2);
    unsigned short* Wt_h  = (unsigned short*)alloc((size_t)3 * 320 * 320 * 2);
    unsigned short* Wt_o  = (unsigned short*)alloc((size_t)320 * 960 * 2);
    int* cnt    = (int*)alloc((size_t)nA * 4);
    int* bucket = (int*)alloc((size_t)nA * CAP * 4);
    unsigned short* input_atom = (unsigned short*)alloc((size_t)nA * HP * 2);
    unsigned short* input_bond = (unsigned short*)alloc((size_t)nB * HP * 2);
    unsigned short* msgA  = (unsigned short*)alloc((size_t)nB * HP * 2);
    unsigned short* msgB  = (unsigned short*)alloc((size_t)nB * HP * 2);
    unsigned short* amsg   = msgB;        // alias: msgB dead after step 3
    unsigned short* atom_h = input_bond;  // alias: input_bond dead after step 3

    if ((size_t)(p - (char*)d_ws) > ws_size) return;  // diagnostic: ws too small

    // adjacency buckets
    hipMemsetAsync(cnt, 0, (size_t)nA * 4, stream);
    fill_k<<<dim3((nB + 255) / 256), dim3(256), 0, stream>>>(b_dst, cnt, bucket, nB);

    // weight prep
    prep_wt<<<dim3((320*160 + 255)/256), dim3(256), 0, stream>>>(W_i_atom, Wt_ia, 133, 160);
    prep_wt<<<dim3((320*160 + 255)/256), dim3(256), 0, stream>>>(W_i_bond, Wt_ib, 147, 160);
    for (int d = 0; d < 3; d++)
        prep_wt<<<dim3((320*320 + 255)/256), dim3(256), 0, stream>>>(
            W_h + (size_t)d * H * H, Wt_h + (size_t)d * 320 * 320, 300, 320);
    prep_wto<<<dim3((320*960 + 255)/256), dim3(256), 0, stream>>>(W_o, Wt_o);

    // input projections
    gemm_k<0><<<dim3(nA/64), dim3(256), 0, stream>>>(
        f_atoms, 133, Wt_ia, nullptr, nullptr, nullptr, nullptr,
        nullptr, nullptr, nullptr, nullptr, input_atom);
    gemm_k<0><<<dim3(nB/64), dim3(256), 0, stream>>>(
        f_bonds, 147, Wt_ib, nullptr, nullptr, nullptr, nullptr,
        nullptr, nullptr, nullptr, nullptr, input_bond);

    // message steps (msg0 = input_bond)
    gemm_k<2><<<dim3(nB/64), dim3(256), 0, stream>>>(
        nullptr, 0, Wt_h + 0 * 320 * 320, input_bond, nullptr, input_bond, nullptr,
        b_src, b2revb, cnt, bucket, msgA);
    gemm_k<2><<<dim3(nB/64), dim3(256), 0, stream>>>(
        nullptr, 0, Wt_h + 1 * 320 * 320, msgA, nullptr, input_bond, nullptr,
        b_src, b2revb, cnt, bucket, msgB);
    gemm_k<2><<<dim3(nB/64), dim3(256), 0, stream>>>(
        nullptr, 0, Wt_h + 2 * 320 * 320, msgB, nullptr, input_bond, nullptr,
        b_src, b2revb, cnt, bucket, msgA);

    // final per-atom aggregation (bf16)
    amsg_k<<<dim3(nA), dim3(320), 0, stream>>>(msgA, cnt, bucket, amsg);

    // atom_h = relu([input_atom | amsg | input_atom*amsg] @ W_o + b_o)
    gemm_k<3><<<dim3(nA/64), dim3(256), 0, stream>>>(
        nullptr, 0, Wt_o, input_atom, amsg, nullptr, b_o,
        nullptr, nullptr, nullptr, nullptr, atom_h);

    // per-molecule mean
    readout_k<<<dim3(nM), dim3(320), 0, stream>>>(atom_h, mol_ids, nA, (float*)d_out);
}